// Round 7
// baseline (456.162 us; speedup 1.0000x reference)
//
#include <hip/hip_runtime.h>
#include <hip/hip_bf16.h>
#include <stdint.h>

using bf16 = __bf16;
using bf16x8 = __attribute__((ext_vector_type(8))) __bf16;
using bf16x4 = __attribute__((ext_vector_type(4))) __bf16;
using f32x4  = __attribute__((ext_vector_type(4))) float;
using u16x8  = __attribute__((ext_vector_type(8))) unsigned short;

#define MFMA16(a,b,c) __builtin_amdgcn_mfma_f32_16x16x32_bf16((a),(b),(c),0,0,0)

__device__ __forceinline__ void gll16(const void* g, void* l) {
  __builtin_amdgcn_global_load_lds(
      (const __attribute__((address_space(1))) uint32_t*)g,
      (__attribute__((address_space(3))) uint32_t*)l, 16, 0, 0);
}

// ---------------- fused fp32 -> bf16 convert (one launch for all 5 tensors) --
__global__ __launch_bounds__(256) void cvt_all_k(
    const float* __restrict__ X, const float* __restrict__ Wq,
    const float* __restrict__ Wk, const float* __restrict__ Wv,
    const float* __restrict__ Wo, bf16* __restrict__ Xb,
    bf16* __restrict__ Wqb, bf16* __restrict__ Wkb,
    bf16* __restrict__ Wvb, bf16* __restrict__ Wob) {
  const int i = blockIdx.x * blockDim.x + threadIdx.x;  // float4 idx, 6291456 total
  const float* src; bf16* dst; int off;
  if (i < 2097152)      { src = X;  dst = Xb;  off = i; }
  else if (i < 3145728) { src = Wq; dst = Wqb; off = i - 2097152; }
  else if (i < 4194304) { src = Wk; dst = Wkb; off = i - 3145728; }
  else if (i < 5242880) { src = Wv; dst = Wvb; off = i - 4194304; }
  else                  { src = Wo; dst = Wob; off = i - 5242880; }
  const float4 v = ((const float4*)src)[off];
  bf16x4 o;
  o[0] = (bf16)v.x; o[1] = (bf16)v.y; o[2] = (bf16)v.z; o[3] = (bf16)v.w;
  ((bf16x4*)dst)[off] = o;
}

// ---------------- GEMM: C[M,N] = A[M,K] * B[N,K]^T ----------------
// BM=256, BN=128, BK=64. 512 thr = 8 waves (2 M x 4 N), per-wave 128x32 out.
// Double-buffered LDS, 2 phases/K-tile (16 MFMA each), counted vmcnt(3) at
// tile boundary (loads in flight across barriers), raw s_barrier x2/K-tile,
// row-XOR swizzle: phys_group = logical_group ^ (row&7), applied on the FULL
// 3-bit group index on both sides (R5 bug: kk term was outside the XOR).
template <typename OutT>
__global__ __launch_bounds__(512, 1) void gemm_bt(
    const bf16* __restrict__ A,
    const bf16* __restrict__ B0, const bf16* __restrict__ B1, const bf16* __restrict__ B2,
    OutT* __restrict__ C0, OutT* __restrict__ C1, OutT* __restrict__ C2,
    int M, int N, int K) {
  // T1 bijective XCD swizzle (nwg % 8 == 0 for our grids)
  const int gx = gridDim.x, gy = gridDim.y;
  const int nwg = gx * gy * gridDim.z;
  int lid = blockIdx.x + gx * (blockIdx.y + gy * blockIdx.z);
  lid = (lid & 7) * (nwg >> 3) + (lid >> 3);
  const int bz = lid / (gx * gy);
  const int rem = lid - bz * (gx * gy);
  const int by = rem / gx, bx = rem - by * gx;

  const bf16* Bm = (bz == 0) ? B0 : (bz == 1 ? B1 : B2);
  OutT* C = (bz == 0) ? C0 : (bz == 1 ? C1 : C2);

  __shared__ bf16 As[2][256 * 64];   // 64 KB
  __shared__ bf16 Bs[2][128 * 64];   // 32 KB

  const int t = threadIdx.x;
  const int w = t >> 6, l = t & 63;
  const int wm = w >> 2, wn = w & 3;
  const int m0 = by * 256, n0 = bx * 128;

  // staging source (per-lane, pre-swizzled column so LDS dest stays linear)
  const int lr8 = l >> 3;                       // row within 8-row group
  const int sc8 = ((l & 7) ^ lr8) * 8;          // swizzled element offset
  const bf16* Agl = A  + (int64_t)(m0 + w * 32 + lr8) * K + sc8;
  const bf16* Bgl = Bm + (int64_t)(n0 + w * 16 + lr8) * K + sc8;

#define STAGE_A(kc, buf, i) \
  gll16(Agl + (int64_t)((i) * 8) * K + (kc), (char*)&As[buf][0] + (w * 4 + (i)) * 1024)
#define STAGE_B(kc, buf, i) \
  gll16(Bgl + (int64_t)((i) * 8) * K + (kc), (char*)&Bs[buf][0] + (w * 2 + (i)) * 1024)

  // read-side fragment addressing; XOR over the FULL group index
  const int swzR = (l & 7) << 4;                // row-parity XOR (bytes)
  const int g0   = (l >> 4) * 16;               // logical byte group base
  const int rowA = wm * 128 + (l & 15);         // + mi*16
  const int rowB = wn * 32 + (l & 15);          // + ni*16

  f32x4 acc[8][2] = {};

  // prologue: stage K-tile 0 into buf 0
  STAGE_A(0, 0, 0); STAGE_A(0, 0, 1); STAGE_B(0, 0, 0);
  STAGE_A(0, 0, 2); STAGE_A(0, 0, 3); STAGE_B(0, 0, 1);

  const int KT = K >> 6;
  for (int kt = 0; kt < KT; ++kt) {
    const int cb = kt & 1, nb = cb ^ 1;
    const int kc = (kt + 1) << 6;
    const bool pf = (kt + 1 < KT);

    // ---- phase 0: issue first half of next tile's stages, counted wait ----
    if (pf) {
      STAGE_A(kc, nb, 0); STAGE_A(kc, nb, 1); STAGE_B(kc, nb, 0);
      asm volatile("s_waitcnt vmcnt(3)" ::: "memory");  // drain this tile's 6
    } else {
      asm volatile("s_waitcnt vmcnt(0)" ::: "memory");
    }
    __builtin_amdgcn_s_barrier();
    asm volatile("" ::: "memory");

    const char* AsB = (const char*)&As[cb][0] + rowA * 128;
    const char* BsB = (const char*)&Bs[cb][0] + rowB * 128;

    bf16x8 b_[2][2];
#pragma unroll
    for (int ni = 0; ni < 2; ++ni)
#pragma unroll
      for (int kk = 0; kk < 2; ++kk)
        b_[ni][kk] = *(const bf16x8*)(BsB + ni * 2048 + ((g0 + kk * 64) ^ swzR));

    {
      bf16x8 a_[4][2];
#pragma unroll
      for (int mi = 0; mi < 4; ++mi)
#pragma unroll
        for (int kk = 0; kk < 2; ++kk)
          a_[mi][kk] = *(const bf16x8*)(AsB + mi * 2048 + ((g0 + kk * 64) ^ swzR));
      __builtin_amdgcn_s_setprio(1);
#pragma unroll
      for (int kk = 0; kk < 2; ++kk)
#pragma unroll
        for (int mi = 0; mi < 4; ++mi)
#pragma unroll
          for (int ni = 0; ni < 2; ++ni)
            acc[mi][ni] = MFMA16(a_[mi][kk], b_[ni][kk], acc[mi][ni]);
      __builtin_amdgcn_s_setprio(0);
    }

    // ---- phase 1: issue second half of next tile's stages ----
    if (pf) { STAGE_A(kc, nb, 2); STAGE_A(kc, nb, 3); STAGE_B(kc, nb, 1); }
    {
      bf16x8 a_[4][2];
#pragma unroll
      for (int mi = 0; mi < 4; ++mi)
#pragma unroll
        for (int kk = 0; kk < 2; ++kk)
          a_[mi][kk] = *(const bf16x8*)(AsB + (4 + mi) * 2048 + ((g0 + kk * 64) ^ swzR));
      __builtin_amdgcn_s_setprio(1);
#pragma unroll
      for (int kk = 0; kk < 2; ++kk)
#pragma unroll
        for (int mi = 0; mi < 4; ++mi)
#pragma unroll
          for (int ni = 0; ni < 2; ++ni)
            acc[4 + mi][ni] = MFMA16(a_[mi][kk], b_[ni][kk], acc[4 + mi][ni]);
      __builtin_amdgcn_s_setprio(0);
    }
    asm volatile("" ::: "memory");
    __builtin_amdgcn_s_barrier();    // end of tile: cb free for restaging
  }

  // epilogue
#pragma unroll
  for (int mi = 0; mi < 8; ++mi) {
    const int row = m0 + wm * 128 + mi * 16 + (l >> 4) * 4;
#pragma unroll
    for (int ni = 0; ni < 2; ++ni) {
      const int col = n0 + wn * 32 + ni * 16 + (l & 15);
#pragma unroll
      for (int j = 0; j < 4; ++j)
        C[(int64_t)(row + j) * N + col] = (OutT)acc[mi][ni][j];
    }
  }
#undef STAGE_A
#undef STAGE_B
}

// ---------------- flash attention (causal + ALiBi + key mask) ----------------
// Swapped-operand MFMAs (lane owns one q-row), exp2-domain softmax, T13
// defer-max (skip rescale when tile max within 11.5 log2 of running max).
__global__ __launch_bounds__(256, 2) void attn_fwd(
    const bf16* __restrict__ Q, const bf16* __restrict__ Kb,
    const bf16* __restrict__ V, const float* __restrict__ mask,
    bf16* __restrict__ O) {
  constexpr int S = 2048, D = 2048, Dh = 128;
  __shared__ bf16 Ks[2][64 * 128];
  __shared__ bf16 Vt[2][128 * 64];
  __shared__ bf16 Pl[4][16 * 68];

  const int t = threadIdx.x, w = t >> 6, l = t & 63;
  const int lq = l & 15, lk = l >> 4;

  const int nwg = gridDim.x * gridDim.y;                 // 1024
  int lid = blockIdx.x + gridDim.x * blockIdx.y;
  lid = (lid & 7) * (nwg >> 3) + (lid >> 3);
  const int bx = lid & 31, by = lid >> 5;

  const int qt = 31 - bx;
  const int q0 = qt * 64;
  const int b = by >> 4, h = by & 15;
  const int swz = (lq & 7) << 4;

  const int kvp = t & 31;
  const int d80 = (t >> 5) * 8;
  const int d81 = d80 + 64;

  bf16x8 qf[4];
  {
    const bf16* Qrow = Q + (int64_t)(b * S + q0 + w * 16 + lq) * D + h * Dh;
#pragma unroll
    for (int kk = 0; kk < 4; ++kk) qf[kk] = *(const bf16x8*)&Qrow[kk * 32 + lk * 8];
  }

  float mr = -1e30f, lr = 0.f;
  f32x4 oacc[8] = {};

  constexpr float LOG2E = 1.4426950408889634f;
  const float scale2 = 0.08838834764831845f * LOG2E;          // log2 domain
  const float slope2 = exp2f(-0.5f * (float)(h + 1)) * LOG2E;
  const int ntiles = qt + 1;
  const int qrow = q0 + w * 16 + lq;

  bf16x8 vA0, vA1, vB0, vB1;

#define LOAD_V(kt)                                                          \
  {                                                                         \
    const bf16* vb = V + (int64_t)(b * S + (kt) * 64 + 2 * kvp) * D + h * Dh; \
    vA0 = *(const bf16x8*)(vb + d80);                                       \
    vA1 = *(const bf16x8*)(vb + D + d80);                                   \
    vB0 = *(const bf16x8*)(vb + d81);                                       \
    vB1 = *(const bf16x8*)(vb + D + d81);                                   \
  }

#define STAGE_K(kt, buf)                                                    \
  {                                                                         \
    _Pragma("unroll")                                                       \
    for (int i = 0; i < 4; ++i) {                                           \
      const int chunk = 4 * w + i;                                          \
      const int r = chunk * 4 + (l >> 4);                                   \
      const int cbl = ((l & 15) * 16) ^ ((r & 7) << 4);                     \
      gll16(Kb + (int64_t)(b * S + (kt) * 64 + r) * D + h * Dh + (cbl >> 1),\
            &Ks[buf][chunk * 512]);                                         \
    }                                                                       \
  }

#define WRITE_V(buf)                                                        \
  {                                                                         \
    const u16x8 u00 = __builtin_bit_cast(u16x8, vA0);                       \
    const u16x8 u01 = __builtin_bit_cast(u16x8, vA1);                       \
    const u16x8 u10 = __builtin_bit_cast(u16x8, vB0);                       \
    const u16x8 u11 = __builtin_bit_cast(u16x8, vB1);                       \
    char* vtb = (char*)&Vt[buf][0];                                         \
    _Pragma("unroll")                                                       \
    for (int jj = 0; jj < 8; ++jj) {                                        \
      const int co = (4 * kvp) ^ (jj << 4);                                 \
      *(uint32_t*)(vtb + (d80 + jj) * 128 + co) =                           \
          (uint32_t)u00[jj] | ((uint32_t)u01[jj] << 16);                    \
      *(uint32_t*)(vtb + (d81 + jj) * 128 + co) =                           \
          (uint32_t)u10[jj] | ((uint32_t)u11[jj] << 16);                    \
    }                                                                       \
  }

  LOAD_V(0);
  STAGE_K(0, 0);
  WRITE_V(0);
  __syncthreads();

  for (int kt = 0; kt < ntiles; ++kt) {
    const int cb = kt & 1, nb = cb ^ 1;
    const int kv0 = kt * 64;
    const bool pft = (kt + 1 < ntiles);
    if (pft) {
      STAGE_K(kt + 1, nb);
      LOAD_V(kt + 1);
    }

    // QK^T swapped: sc[ni][j] = S[kv = kv0+ni*16+lk*4+j][q = qrow]
    f32x4 sc[4];
#pragma unroll
    for (int ni = 0; ni < 4; ++ni) {
      const char* krow = (const char*)&Ks[cb][(ni * 16 + lq) * 128];
      f32x4 a = {};
#pragma unroll
      for (int kk = 0; kk < 4; ++kk) {
        bf16x8 kf = *(const bf16x8*)(krow + ((kk * 64 + lk * 16) ^ swz));
        a = MFMA16(kf, qf[kk], a);
      }
      sc[ni] = a;
    }

    // scale + ALiBi + causal + key-mask (log2 domain, lane-local)
#pragma unroll
    for (int ni = 0; ni < 4; ++ni) {
      const float4 mv = *(const float4*)&mask[b * S + kv0 + ni * 16 + lk * 4];
      const float* mvp = (const float*)&mv;
#pragma unroll
      for (int j = 0; j < 4; ++j) {
        const int kcol = kv0 + ni * 16 + lk * 4 + j;
        float s = sc[ni][j] * scale2 - slope2 * (float)(qrow - kcol);
        s = (kcol > qrow) ? -1e30f : s;
        sc[ni][j] = s * mvp[j];
      }
    }

    // online softmax: lane-local max + 2 shfls; T13 defer-max rescale skip
    float mj = sc[0][0];
#pragma unroll
    for (int ni = 0; ni < 4; ++ni)
#pragma unroll
      for (int j = 0; j < 4; ++j) mj = fmaxf(mj, sc[ni][j]);
    mj = fmaxf(mj, __shfl_xor(mj, 16));
    mj = fmaxf(mj, __shfl_xor(mj, 32));
    if (!__all(mj - mr <= 11.5f)) {      // wave-uniform branch
      const float mnew = fmaxf(mr, mj);
      const float r2 = exp2f(mr - mnew);
      lr *= r2;
#pragma unroll
      for (int df = 0; df < 8; ++df)
#pragma unroll
        for (int j = 0; j < 4; ++j) oacc[df][j] *= r2;
      mr = mnew;
    }
    float ps = 0.f;
#pragma unroll
    for (int ni = 0; ni < 4; ++ni)
#pragma unroll
      for (int j = 0; j < 4; ++j) {
        const float p = exp2f(sc[ni][j] - mr);
        sc[ni][j] = p;
        ps += p;
      }
    ps += __shfl_xor(ps, 16);
    ps += __shfl_xor(ps, 32);
    lr += ps;

    // P -> per-wave LDS: 4x packed 8B writes
#pragma unroll
    for (int ni = 0; ni < 4; ++ni) {
      bf16x4 pb;
#pragma unroll
      for (int j = 0; j < 4; ++j) pb[j] = (bf16)sc[ni][j];
      *(bf16x4*)&Pl[w][lq * 68 + ni * 16 + lk * 4] = pb;
    }

    bf16x8 pf0 = *(const bf16x8*)&Pl[w][lq * 68 + lk * 8];
    bf16x8 pf1 = *(const bf16x8*)&Pl[w][lq * 68 + 32 + lk * 8];

    // PV swapped: A=V^T (rows d), B=P (cols q)
#pragma unroll
    for (int df = 0; df < 8; ++df) {
      const char* vrow = (const char*)&Vt[cb][(df * 16 + lq) * 64];
      bf16x8 vf0 = *(const bf16x8*)(vrow + ((lk * 16) ^ swz));
      oacc[df] = MFMA16(vf0, pf0, oacc[df]);
      bf16x8 vf1 = *(const bf16x8*)(vrow + ((64 + lk * 16) ^ swz));
      oacc[df] = MFMA16(vf1, pf1, oacc[df]);
    }

    if (pft) WRITE_V(nb);
    __syncthreads();
  }

  const float inv = 1.0f / lr;
  bf16* orow = O + (int64_t)(b * S + qrow) * D + h * Dh;
#pragma unroll
  for (int df = 0; df < 8; ++df) {
    bf16x4 ob;
#pragma unroll
    for (int j = 0; j < 4; ++j) ob[j] = (bf16)(oacc[df][j] * inv);
    *(bf16x4*)&orow[df * 16 + lk * 4] = ob;
  }
#undef LOAD_V
#undef STAGE_K
#undef WRITE_V
}

// ---------------- launch ----------------
extern "C" void kernel_launch(void* const* d_in, const int* in_sizes, int n_in,
                              void* d_out, int out_size, void* d_ws, size_t ws_size,
                              hipStream_t stream) {
  const float* X    = (const float*)d_in[0];
  const float* mask = (const float*)d_in[1];
  const float* Wq   = (const float*)d_in[2];
  const float* Wk   = (const float*)d_in[3];
  const float* Wv   = (const float*)d_in[4];
  const float* Wo   = (const float*)d_in[5];
  float* out = (float*)d_out;

  bf16* ws = (bf16*)d_ws;
  bf16* Xb  = ws;                 // 4096*2048
  bf16* Wqb = ws + 8388608;       // 2048*2048 each
  bf16* Wkb = ws + 12582912;
  bf16* Wvb = ws + 16777216;
  bf16* Wob = ws + 20971520;
  bf16* Qb  = ws + 25165824;      // 4096*2048 each
  bf16* Kb  = ws + 33554432;
  bf16* Vb  = ws + 41943040;
  bf16* Ab  = ws + 50331648;      // 4096*2048

  cvt_all_k<<<24576, 256, 0, stream>>>(X, Wq, Wk, Wv, Wo,
                                       Xb, Wqb, Wkb, Wvb, Wob);

  gemm_bt<bf16><<<dim3(16, 16, 3), 512, 0, stream>>>(
      Xb, Wqb, Wkb, Wvb, Qb, Kb, Vb, 4096, 2048, 2048);

  attn_fwd<<<dim3(32, 32), 256, 0, stream>>>(Qb, Kb, Vb, mask, Ab);

  gemm_bt<float><<<dim3(16, 16, 1), 512, 0, stream>>>(
      Ab, Wob, Wob, Wob, out, out, out, 4096, 2048, 2048);
}